// Round 1
// baseline (2111.023 us; speedup 1.0000x reference)
//
#include <hip/hip_runtime.h>
#include <hip/hip_bf16.h>
#include <math.h>

#define T_TOK 2048
#define H_DIM 1024
#define NHH 16
#define NKVH 4
#define HD 64
#define QKV_N 1536   // (16 + 2*4) * 64
#define NE 64
#define NGRP 8
#define TKG 4
#define TOPKK 8
#define EI 256
#define ISH 512
#define NPOS (T_TOK * TOPKK)   // 16384 expert-token slots

// ---------------- RMSNorm ----------------
__global__ void rmsnorm_k(const float* __restrict__ x, const float* __restrict__ w,
                          float* __restrict__ out) {
  const int t = blockIdx.x;
  const int tid = threadIdx.x;
  const float* xp = x + (size_t)t * H_DIM;
  float s = 0.f;
  for (int i = tid; i < H_DIM; i += 256) { float v = xp[i]; s += v * v; }
#pragma unroll
  for (int off = 32; off >= 1; off >>= 1) s += __shfl_xor(s, off);
  __shared__ float red[4];
  if ((tid & 63) == 0) red[tid >> 6] = s;
  __syncthreads();
  float tot = red[0] + red[1] + red[2] + red[3];
  float r = rsqrtf(tot / (float)H_DIM + 1e-6f);
  float* op = out + (size_t)t * H_DIM;
  for (int i = tid; i < H_DIM; i += 256) op[i] = xp[i] * r * w[i];
}

// ---------------- generic f32 GEMM: C = A@B (+add0)(+add1) ----------------
// A [M,K] row-major, B [K,N] row-major. M,N multiples of 64, K multiple of 16.
__global__ void gemm64_k(const float* __restrict__ A, const float* __restrict__ B,
                         const float* __restrict__ add0, const float* __restrict__ add1,
                         float* __restrict__ C, int M, int N, int K) {
  __shared__ float As[16][68];
  __shared__ float Bs[16][68];
  const int tid = threadIdx.x;
  const int tx = tid & 15, ty = tid >> 4;
  const int m0 = blockIdx.y * 64, n0 = blockIdx.x * 64;
  const int am = tid >> 2, ak = (tid & 3) << 2;
  const int bk = tid >> 4, bn = (tid & 15) << 2;
  float acc[4][4] = {};
  for (int kk = 0; kk < K; kk += 16) {
    float4 av = *(const float4*)(A + (size_t)(m0 + am) * K + kk + ak);
    As[ak + 0][am] = av.x; As[ak + 1][am] = av.y;
    As[ak + 2][am] = av.z; As[ak + 3][am] = av.w;
    *(float4*)&Bs[bk][bn] = *(const float4*)(B + (size_t)(kk + bk) * N + n0 + bn);
    __syncthreads();
#pragma unroll
    for (int k = 0; k < 16; k++) {
      const float4 a = *(const float4*)&As[k][ty << 2];
      const float4 b = *(const float4*)&Bs[k][tx << 2];
      const float ar[4] = {a.x, a.y, a.z, a.w};
      const float br[4] = {b.x, b.y, b.z, b.w};
#pragma unroll
      for (int i = 0; i < 4; i++)
#pragma unroll
        for (int j = 0; j < 4; j++) acc[i][j] += ar[i] * br[j];
    }
    __syncthreads();
  }
#pragma unroll
  for (int i = 0; i < 4; i++) {
    const int m = m0 + (ty << 2) + i;
#pragma unroll
    for (int j = 0; j < 4; j++) {
      const int n = n0 + (tx << 2) + j;
      float v = acc[i][j];
      if (add0) v += add0[(size_t)m * N + n];
      if (add1) v += add1[(size_t)m * N + n];
      C[(size_t)m * N + n] = v;
    }
  }
}

// ---------------- RoPE (neox, in-place on q and k regions of qkv) ----------------
__global__ void rope_k(float* __restrict__ qkv, const int* __restrict__ positions) {
  const int t = blockIdx.x, h = blockIdx.y;   // h in [0, 20): 16 q heads + 4 k heads
  const int i = threadIdx.x;                  // 0..31
  const double pos = (double)positions[t];
  const double inv = pow(10000.0, -2.0 * (double)i / 64.0);
  const double f = pos * inv;
  const float c = (float)cos(f), sn = (float)sin(f);
  float* p = qkv + (size_t)t * QKV_N + h * HD;
  const float x1 = p[i], x2 = p[i + 32];
  p[i] = x1 * c - x2 * sn;
  p[i + 32] = x2 * c + x1 * sn;
}

// ---------------- attention: block = (query t, kv head g), 4 waves = 4 q heads ----------------
__global__ void attn_k(const float* __restrict__ qkv, float* __restrict__ attn) {
  const int t = blockIdx.x, g = blockIdx.y;
  const int tid = threadIdx.x;
  const int w = tid >> 6, lane = tid & 63;
  __shared__ float Kt[64][65];
  __shared__ float Vt[64][65];
  __shared__ float qs[4][64];
  {
    const int hh = tid >> 6, d = tid & 63;
    qs[hh][d] = qkv[(size_t)t * QKV_N + (g * 4 + hh) * HD + d];
  }
  __syncthreads();
  const float* kbase = qkv + NHH * HD + g * HD;
  const float* vbase = qkv + (NHH + NKVH) * HD + g * HD;
  float m = -1e30f, l = 0.f, acc = 0.f;
  for (int s0 = 0; s0 <= t; s0 += 64) {
    for (int idx = tid; idx < 64 * 64; idx += 256) {
      const int j = idx >> 6, d = idx & 63;
      const size_t row = (size_t)(s0 + j) * QKV_N;
      Kt[j][d] = kbase[row + d];
      Vt[j][d] = vbase[row + d];
    }
    __syncthreads();
    float dot = 0.f;
#pragma unroll
    for (int d = 0; d < 64; d++) dot += qs[w][d] * Kt[lane][d];
    const float sc = (s0 + lane <= t) ? dot * 0.125f : -1e30f;
    float tm = sc;
#pragma unroll
    for (int off = 32; off >= 1; off >>= 1) tm = fmaxf(tm, __shfl_xor(tm, off));
    const float mnew = fmaxf(m, tm);
    const float p = expf(sc - mnew);
    const float alpha = expf(m - mnew);
    float ps = p;
#pragma unroll
    for (int off = 32; off >= 1; off >>= 1) ps += __shfl_xor(ps, off);
    l = l * alpha + ps;
    acc *= alpha;
    for (int j = 0; j < 64; j++) acc += __shfl(p, j) * Vt[j][lane];
    m = mnew;
    __syncthreads();
  }
  attn[(size_t)t * (NHH * HD) + (g * 4 + w) * HD + lane] = acc / l;
}

// ---------------- router logits: lane e computes h2[t] . gate_w[e] ----------------
__global__ void gate_logits_k(const float* __restrict__ h2, const float* __restrict__ gw,
                              float* __restrict__ logits) {
  const int t = blockIdx.x;
  const int e = threadIdx.x;  // 64
  const float* hp = h2 + (size_t)t * H_DIM;
  const float* gp = gw + (size_t)e * H_DIM;
  float s = 0.f;
  for (int i = 0; i < H_DIM; i += 4) {
    const float4 h4 = *(const float4*)(hp + i);
    const float4 g4 = *(const float4*)(gp + i);
    s += h4.x * g4.x + h4.y * g4.y + h4.z * g4.z + h4.w * g4.w;
  }
  logits[t * NE + e] = s;
}

// ---------------- routing: one thread per token (sequential, matches lax.top_k ties) ------
__global__ void route_k(const float* __restrict__ logits, const float* __restrict__ ebias,
                        int* __restrict__ topk_ids, float* __restrict__ topk_w) {
  const int t = blockIdx.x * 64 + threadIdx.x;
  if (t >= T_TOK) return;
  float s[NE], sc[NE];
  const float* lp = logits + t * NE;
#pragma unroll
  for (int e = 0; e < NE; e++) {
    const float v = 1.f / (1.f + expf(-lp[e]));
    s[e] = v;
    sc[e] = v + ebias[e];
  }
  float gsc[NGRP];
#pragma unroll
  for (int gi = 0; gi < NGRP; gi++) {
    float m1 = -1e30f, m2 = -1e30f;
#pragma unroll
    for (int j = 0; j < 8; j++) {
      const float v = sc[gi * 8 + j];
      if (v > m1) { m2 = m1; m1 = v; } else if (v > m2) m2 = v;
    }
    gsc[gi] = m1 + m2;
  }
  unsigned gmask = 0;
  for (int k2 = 0; k2 < TKG; k2++) {
    int bi = 0; float b = -3.4e38f;
#pragma unroll
    for (int gi = 0; gi < NGRP; gi++)
      if (!((gmask >> gi) & 1u) && gsc[gi] > b) { b = gsc[gi]; bi = gi; }
    gmask |= 1u << bi;
  }
  unsigned long long esel = 0ull;
  float wsum = 0.f;
  int ids[TOPKK]; float wv[TOPKK];
  for (int k2 = 0; k2 < TOPKK; k2++) {
    int bi = 0; float b = -3.4e38f;
    for (int e = 0; e < NE; e++) {
      if (((gmask >> (e >> 3)) & 1u) && !((esel >> e) & 1ull) && sc[e] > b) { b = sc[e]; bi = e; }
    }
    esel |= 1ull << bi;
    ids[k2] = bi;
    wv[k2] = s[bi];
    wsum += wv[k2];
  }
  const float norm = 2.5f / (wsum + 1e-20f);
#pragma unroll
  for (int k2 = 0; k2 < TOPKK; k2++) {
    topk_ids[t * TOPKK + k2] = ids[k2];
    topk_w[t * TOPKK + k2] = wv[k2] * norm;
  }
}

// ---------------- expert-token list construction ----------------
__global__ void count_k(const int* __restrict__ ids, int* __restrict__ counts) {
  const int idx = blockIdx.x * 256 + threadIdx.x;
  if (idx < NPOS) atomicAdd(&counts[ids[idx]], 1);
}

__global__ void offsets_k(const int* __restrict__ counts, int* __restrict__ offsets,
                          int* __restrict__ cursor) {
  if (threadIdx.x == 0 && blockIdx.x == 0) {
    int acc = 0;
    for (int e = 0; e < NE; e++) { offsets[e] = acc; cursor[e] = acc; acc += counts[e]; }
    offsets[NE] = acc;
  }
}

__global__ void scatter_k(const int* __restrict__ ids, const float* __restrict__ wts,
                          int* __restrict__ cursor, int* __restrict__ perm_tok,
                          float* __restrict__ perm_w) {
  const int idx = blockIdx.x * 256 + threadIdx.x;
  if (idx >= NPOS) return;
  const int e = ids[idx];
  const int pos = atomicAdd(&cursor[e], 1);
  perm_tok[pos] = idx >> 3;   // token
  perm_w[pos] = wts[idx];
}

// ---------------- routed experts: gate+up+silu ----------------
__global__ void moe_gateup_k(const float* __restrict__ h2, const float* __restrict__ we_gate,
                             const float* __restrict__ we_up, const int* __restrict__ perm_tok,
                             const int* __restrict__ offsets, float* __restrict__ act) {
  const int e = blockIdx.z;
  const int base = offsets[e];
  const int cnt = offsets[e + 1] - base;
  const int n0 = blockIdx.y * 64;
  if (n0 >= cnt) return;
  const int i0 = blockIdx.x * 64;
  __shared__ float As[16][68];
  __shared__ float Bg[16][68];
  __shared__ float Bu[16][68];
  __shared__ int toks[64];
  const int tid = threadIdx.x;
  if (tid < 64) toks[tid] = perm_tok[base + min(n0 + tid, cnt - 1)];
  __syncthreads();
  const float* wg = we_gate + (size_t)e * H_DIM * EI;
  const float* wu = we_up + (size_t)e * H_DIM * EI;
  const int tx = tid & 15, ty = tid >> 4;
  const int am = tid >> 2, ak = (tid & 3) << 2;
  const int bk = tid >> 4, bn = (tid & 15) << 2;
  float accg[4][4] = {}, accu[4][4] = {};
  for (int kk = 0; kk < H_DIM; kk += 16) {
    const float4 av = *(const float4*)(h2 + (size_t)toks[am] * H_DIM + kk + ak);
    As[ak + 0][am] = av.x; As[ak + 1][am] = av.y;
    As[ak + 2][am] = av.z; As[ak + 3][am] = av.w;
    *(float4*)&Bg[bk][bn] = *(const float4*)(wg + (size_t)(kk + bk) * EI + i0 + bn);
    *(float4*)&Bu[bk][bn] = *(const float4*)(wu + (size_t)(kk + bk) * EI + i0 + bn);
    __syncthreads();
#pragma unroll
    for (int k = 0; k < 16; k++) {
      const float4 a = *(const float4*)&As[k][ty << 2];
      const float4 bg = *(const float4*)&Bg[k][tx << 2];
      const float4 bu = *(const float4*)&Bu[k][tx << 2];
      const float ar[4] = {a.x, a.y, a.z, a.w};
      const float bgr[4] = {bg.x, bg.y, bg.z, bg.w};
      const float bur[4] = {bu.x, bu.y, bu.z, bu.w};
#pragma unroll
      for (int i = 0; i < 4; i++)
#pragma unroll
        for (int j = 0; j < 4; j++) {
          accg[i][j] += ar[i] * bgr[j];
          accu[i][j] += ar[i] * bur[j];
        }
    }
    __syncthreads();
  }
#pragma unroll
  for (int i = 0; i < 4; i++) {
    const int n = n0 + (ty << 2) + i;
    if (n < cnt) {
#pragma unroll
      for (int j = 0; j < 4; j++) {
        const float gv = accg[i][j], uv = accu[i][j];
        act[(size_t)(base + n) * EI + i0 + (tx << 2) + j] = gv / (1.f + expf(-gv)) * uv;
      }
    }
  }
}

// ---------------- routed experts: down proj, weighted atomic accumulate into y -------
__global__ void moe_down_k(const float* __restrict__ act, const float* __restrict__ we_down,
                           const int* __restrict__ perm_tok, const float* __restrict__ perm_w,
                           const int* __restrict__ offsets, float* __restrict__ y) {
  const int e = blockIdx.z;
  const int base = offsets[e];
  const int cnt = offsets[e + 1] - base;
  const int n0 = blockIdx.y * 64;
  if (n0 >= cnt) return;
  const int h0 = blockIdx.x * 64;
  __shared__ float As[16][68];
  __shared__ float Bs[16][68];
  __shared__ int toks[64];
  __shared__ float wts[64];
  const int tid = threadIdx.x;
  if (tid < 64) {
    const int r = min(n0 + tid, cnt - 1);
    toks[tid] = perm_tok[base + r];
    wts[tid] = perm_w[base + r];
  }
  __syncthreads();
  const float* wd = we_down + (size_t)e * EI * H_DIM;
  const int tx = tid & 15, ty = tid >> 4;
  const int am = tid >> 2, ak = (tid & 3) << 2;
  const int bk = tid >> 4, bn = (tid & 15) << 2;
  const int ar_row = base + min(n0 + am, cnt - 1);
  float acc[4][4] = {};
  for (int kk = 0; kk < EI; kk += 16) {
    const float4 av = *(const float4*)(act + (size_t)ar_row * EI + kk + ak);
    As[ak + 0][am] = av.x; As[ak + 1][am] = av.y;
    As[ak + 2][am] = av.z; As[ak + 3][am] = av.w;
    *(float4*)&Bs[bk][bn] = *(const float4*)(wd + (size_t)(kk + bk) * H_DIM + h0 + bn);
    __syncthreads();
#pragma unroll
    for (int k = 0; k < 16; k++) {
      const float4 a = *(const float4*)&As[k][ty << 2];
      const float4 b = *(const float4*)&Bs[k][tx << 2];
      const float ar[4] = {a.x, a.y, a.z, a.w};
      const float br[4] = {b.x, b.y, b.z, b.w};
#pragma unroll
      for (int i = 0; i < 4; i++)
#pragma unroll
        for (int j = 0; j < 4; j++) acc[i][j] += ar[i] * br[j];
    }
    __syncthreads();
  }
#pragma unroll
  for (int i = 0; i < 4; i++) {
    const int n = n0 + (ty << 2) + i;
    if (n < cnt) {
      const float wv = wts[(ty << 2) + i];
      const int t = toks[(ty << 2) + i];
#pragma unroll
      for (int j = 0; j < 4; j++)
        atomicAdd(&y[(size_t)t * H_DIM + h0 + (tx << 2) + j], wv * acc[i][j]);
    }
  }
}

// ---------------- shared expert activation ----------------
__global__ void sact_k(const float* __restrict__ gu, float* __restrict__ sa) {
  const int idx = blockIdx.x * 256 + threadIdx.x;   // < T*512
  const int t = idx >> 9, i = idx & 511;
  const float g = gu[(size_t)t * 1024 + i];
  const float u = gu[(size_t)t * 1024 + 512 + i];
  sa[idx] = g / (1.f + expf(-g)) * u;
}

// ---------------- launch ----------------
extern "C" void kernel_launch(void* const* d_in, const int* in_sizes, int n_in,
                              void* d_out, int out_size, void* d_ws, size_t ws_size,
                              hipStream_t stream) {
  const float* x         = (const float*)d_in[0];
  const int*   positions = (const int*)d_in[1];
  const float* ln1_w     = (const float*)d_in[2];
  const float* w_qkv     = (const float*)d_in[3];
  const float* w_o       = (const float*)d_in[4];
  const float* ln2_w     = (const float*)d_in[5];
  const float* gate_w    = (const float*)d_in[6];
  const float* ebias     = (const float*)d_in[7];
  const float* we_gate   = (const float*)d_in[8];
  const float* we_up     = (const float*)d_in[9];
  const float* we_down   = (const float*)d_in[10];
  const float* ws_gateup = (const float*)d_in[11];
  const float* ws_down   = (const float*)d_in[12];
  float* out = (float*)d_out;

  char* wsp = (char*)d_ws;
  size_t off = 0;
  auto alloc = [&](size_t bytes) {
    void* p = wsp + off;
    off += (bytes + 255) & ~(size_t)255;
    return p;
  };
  float* h1      = (float*)alloc((size_t)T_TOK * H_DIM * 4);
  float* qkv     = (float*)alloc((size_t)T_TOK * QKV_N * 4);
  float* attn    = (float*)alloc((size_t)T_TOK * H_DIM * 4);
  float* resid1  = (float*)alloc((size_t)T_TOK * H_DIM * 4);
  float* h2      = (float*)alloc((size_t)T_TOK * H_DIM * 4);
  float* logits  = (float*)alloc((size_t)T_TOK * NE * 4);
  int*   tids    = (int*)alloc((size_t)NPOS * 4);
  float* tw      = (float*)alloc((size_t)NPOS * 4);
  int*   counts  = (int*)alloc(NE * 4);
  int*   offs    = (int*)alloc((NE + 1) * 4);
  int*   cursor  = (int*)alloc(NE * 4);
  int*   ptok    = (int*)alloc((size_t)NPOS * 4);
  float* pw      = (float*)alloc((size_t)NPOS * 4);
  float* act     = (float*)alloc((size_t)NPOS * EI * 4);
  float* y       = (float*)alloc((size_t)T_TOK * H_DIM * 4);
  float* gu      = (float*)alloc((size_t)T_TOK * 1024 * 4);
  float* sa      = (float*)alloc((size_t)T_TOK * ISH * 4);
  (void)ws_size; (void)in_sizes; (void)n_in; (void)out_size;

  hipMemsetAsync(counts, 0, NE * 4, stream);
  hipMemsetAsync(y, 0, (size_t)T_TOK * H_DIM * 4, stream);

  // attention block
  rmsnorm_k<<<T_TOK, 256, 0, stream>>>(x, ln1_w, h1);
  gemm64_k<<<dim3(QKV_N / 64, T_TOK / 64), 256, 0, stream>>>(
      h1, w_qkv, nullptr, nullptr, qkv, T_TOK, QKV_N, H_DIM);
  rope_k<<<dim3(T_TOK, NHH + NKVH), 32, 0, stream>>>(qkv, positions);
  attn_k<<<dim3(T_TOK, NKVH), 256, 0, stream>>>(qkv, attn);
  gemm64_k<<<dim3(H_DIM / 64, T_TOK / 64), 256, 0, stream>>>(
      attn, w_o, x, nullptr, resid1, T_TOK, H_DIM, H_DIM);

  // MoE block
  rmsnorm_k<<<T_TOK, 256, 0, stream>>>(resid1, ln2_w, h2);
  gate_logits_k<<<T_TOK, 64, 0, stream>>>(h2, gate_w, logits);
  route_k<<<T_TOK / 64, 64, 0, stream>>>(logits, ebias, tids, tw);
  count_k<<<NPOS / 256, 256, 0, stream>>>(tids, counts);
  offsets_k<<<1, 1, 0, stream>>>(counts, offs, cursor);
  scatter_k<<<NPOS / 256, 256, 0, stream>>>(tids, tw, cursor, ptok, pw);
  moe_gateup_k<<<dim3(EI / 64, T_TOK / 64, NE), 256, 0, stream>>>(
      h2, we_gate, we_up, ptok, offs, act);
  moe_down_k<<<dim3(H_DIM / 64, T_TOK / 64, NE), 256, 0, stream>>>(
      act, we_down, ptok, pw, offs, y);

  // shared expert + final combine
  gemm64_k<<<dim3(1024 / 64, T_TOK / 64), 256, 0, stream>>>(
      h2, ws_gateup, nullptr, nullptr, gu, T_TOK, 1024, H_DIM);
  sact_k<<<(T_TOK * ISH) / 256, 256, 0, stream>>>(gu, sa);
  gemm64_k<<<dim3(H_DIM / 64, T_TOK / 64), 256, 0, stream>>>(
      sa, ws_down, resid1, y, out, T_TOK, H_DIM, ISH);
}

// Round 2
// 1494.582 us; speedup vs baseline: 1.4125x; 1.4125x over previous
//
#include <hip/hip_runtime.h>
#include <hip/hip_bf16.h>
#include <math.h>

#define T_TOK 2048
#define H_DIM 1024
#define NHH 16
#define NKVH 4
#define HD 64
#define QKV_N 1536   // (16 + 2*4) * 64
#define NE 64
#define NGRP 8
#define TKG 4
#define TOPKK 8
#define EI 256
#define ISH 512
#define NPOS (T_TOK * TOPKK)   // 16384 expert-token slots

// ---------------- RMSNorm ----------------
__global__ void rmsnorm_k(const float* __restrict__ x, const float* __restrict__ w,
                          float* __restrict__ out) {
  const int t = blockIdx.x;
  const int tid = threadIdx.x;
  const float* xp = x + (size_t)t * H_DIM;
  float s = 0.f;
  for (int i = tid; i < H_DIM; i += 256) { float v = xp[i]; s += v * v; }
#pragma unroll
  for (int off = 32; off >= 1; off >>= 1) s += __shfl_xor(s, off);
  __shared__ float red[4];
  if ((tid & 63) == 0) red[tid >> 6] = s;
  __syncthreads();
  float tot = red[0] + red[1] + red[2] + red[3];
  float r = rsqrtf(tot / (float)H_DIM + 1e-6f);
  float* op = out + (size_t)t * H_DIM;
  for (int i = tid; i < H_DIM; i += 256) op[i] = xp[i] * r * w[i];
}

// ---------------- generic f32 GEMM: C = A@B (+add0)(+add1) ----------------
__global__ void gemm64_k(const float* __restrict__ A, const float* __restrict__ B,
                         const float* __restrict__ add0, const float* __restrict__ add1,
                         float* __restrict__ C, int M, int N, int K) {
  __shared__ float As[16][68];
  __shared__ float Bs[16][68];
  const int tid = threadIdx.x;
  const int tx = tid & 15, ty = tid >> 4;
  const int m0 = blockIdx.y * 64, n0 = blockIdx.x * 64;
  const int am = tid >> 2, ak = (tid & 3) << 2;
  const int bk = tid >> 4, bn = (tid & 15) << 2;
  float acc[4][4] = {};
  for (int kk = 0; kk < K; kk += 16) {
    float4 av = *(const float4*)(A + (size_t)(m0 + am) * K + kk + ak);
    As[ak + 0][am] = av.x; As[ak + 1][am] = av.y;
    As[ak + 2][am] = av.z; As[ak + 3][am] = av.w;
    *(float4*)&Bs[bk][bn] = *(const float4*)(B + (size_t)(kk + bk) * N + n0 + bn);
    __syncthreads();
#pragma unroll
    for (int k = 0; k < 16; k++) {
      const float4 a = *(const float4*)&As[k][ty << 2];
      const float4 b = *(const float4*)&Bs[k][tx << 2];
      const float ar[4] = {a.x, a.y, a.z, a.w};
      const float br[4] = {b.x, b.y, b.z, b.w};
#pragma unroll
      for (int i = 0; i < 4; i++)
#pragma unroll
        for (int j = 0; j < 4; j++) acc[i][j] += ar[i] * br[j];
    }
    __syncthreads();
  }
#pragma unroll
  for (int i = 0; i < 4; i++) {
    const int m = m0 + (ty << 2) + i;
#pragma unroll
    for (int j = 0; j < 4; j++) {
      const int n = n0 + (tx << 2) + j;
      float v = acc[i][j];
      if (add0) v += add0[(size_t)m * N + n];
      if (add1) v += add1[(size_t)m * N + n];
      C[(size_t)m * N + n] = v;
    }
  }
}

// ---------------- RoPE (neox, in-place on q and k regions of qkv), f32 ----------------
__global__ void rope_k(float* __restrict__ qkv, const int* __restrict__ positions) {
  const int t = blockIdx.x, h = blockIdx.y;   // h in [0, 20): 16 q heads + 4 k heads
  const int i = threadIdx.x;                  // 0..31
  // inv = 10000^(-i/32) = 2^(-i/32 * log2(10000))
  const float inv = exp2f((float)i * (-13.287712379549449f / 32.0f));
  const float f = (float)positions[t] * inv;
  float sn, c;
  sincosf(f, &sn, &c);
  float* p = qkv + (size_t)t * QKV_N + h * HD;
  const float x1 = p[i], x2 = p[i + 32];
  p[i] = x1 * c - x2 * sn;
  p[i + 32] = x2 * c + x1 * sn;
}

// ---------------- flash attention: block = (64-query tile, head) ----------------
// 256 threads = 4 waves; 4x4 register tile per thread for S and O.
// LDS: Qt[d][i] (pre-scaled), Kd[d][j] (reused as Ps[j][i] for PV), Vt[j][d].
__global__ __launch_bounds__(256) void attn_k(const float* __restrict__ qkv,
                                              float* __restrict__ attn) {
  const int qt = (T_TOK / 64 - 1) - blockIdx.x;   // heavy tiles first
  const int h = blockIdx.y;                       // 0..15
  const int g = h >> 2;                           // kv head
  const int tid = threadIdx.x;
  const int tx = tid & 15, ty = tid >> 4;
  __shared__ float Qt[64][68];   // [dim][query]
  __shared__ float Kd[64][68];   // [dim][key]; reused as Ps[key][query]
  __shared__ float Vt[64][68];   // [key][dim]
  // load Q tile (pre-scale by 1/sqrt(D))
  {
    const int i = tid & 63, dg = tid >> 6;
    const float* qp = qkv + (size_t)(qt * 64 + i) * QKV_N + h * HD;
#pragma unroll
    for (int r = 0; r < 4; r++) {
      const int d = dg * 16 + r * 4;
      const float4 v = *(const float4*)(qp + d);
      Qt[d + 0][i] = v.x * 0.125f;
      Qt[d + 1][i] = v.y * 0.125f;
      Qt[d + 2][i] = v.z * 0.125f;
      Qt[d + 3][i] = v.w * 0.125f;
    }
  }
  float m[4], l[4], acc[4][4];
#pragma unroll
  for (int i = 0; i < 4; i++) {
    m[i] = -1e30f; l[i] = 0.f;
#pragma unroll
    for (int j = 0; j < 4; j++) acc[i][j] = 0.f;
  }
  const float* kbase = qkv + NHH * HD + g * HD;
  const float* vbase = qkv + (NHH + NKVH) * HD + g * HD;
  const int jj_stage = tid & 63, dg_stage = tid >> 6;
  for (int s0 = 0; s0 <= qt * 64; s0 += 64) {
    __syncthreads();   // prior PV reads of Kd/Vt done (and Qt ready on iter 0)
    // stage K (dim-major) and V (key-major)
    {
      const float* kp = kbase + (size_t)(s0 + jj_stage) * QKV_N;
      const float* vp = vbase + (size_t)(s0 + jj_stage) * QKV_N;
#pragma unroll
      for (int r = 0; r < 4; r++) {
        const int d = dg_stage * 16 + r * 4;
        const float4 k4 = *(const float4*)(kp + d);
        Kd[d + 0][jj_stage] = k4.x; Kd[d + 1][jj_stage] = k4.y;
        Kd[d + 2][jj_stage] = k4.z; Kd[d + 3][jj_stage] = k4.w;
        *(float4*)&Vt[jj_stage][d] = *(const float4*)(vp + d);
      }
    }
    __syncthreads();
    // S = (Q*scale) K^T  — register tile
    float s[4][4] = {};
#pragma unroll 8
    for (int d = 0; d < 64; d++) {
      const float4 a = *(const float4*)&Qt[d][ty << 2];
      const float4 b = *(const float4*)&Kd[d][tx << 2];
      const float ar[4] = {a.x, a.y, a.z, a.w};
      const float br[4] = {b.x, b.y, b.z, b.w};
#pragma unroll
      for (int i = 0; i < 4; i++)
#pragma unroll
        for (int j = 0; j < 4; j++) s[i][j] += ar[i] * br[j];
    }
    // causal mask on the diagonal tile
    if (s0 == qt * 64) {
#pragma unroll
      for (int i = 0; i < 4; i++)
#pragma unroll
        for (int j = 0; j < 4; j++)
          if ((tx << 2) + j > (ty << 2) + i) s[i][j] = -1e30f;
    }
    // online softmax update (row groups share ty; reduce across tx lanes)
#pragma unroll
    for (int i = 0; i < 4; i++) {
      float mx = fmaxf(fmaxf(s[i][0], s[i][1]), fmaxf(s[i][2], s[i][3]));
#pragma unroll
      for (int off = 1; off <= 8; off <<= 1) mx = fmaxf(mx, __shfl_xor(mx, off));
      const float mnew = fmaxf(m[i], mx);
      const float alpha = expf(m[i] - mnew);
      float ps = 0.f;
#pragma unroll
      for (int j = 0; j < 4; j++) { const float p = expf(s[i][j] - mnew); s[i][j] = p; ps += p; }
#pragma unroll
      for (int off = 1; off <= 8; off <<= 1) ps += __shfl_xor(ps, off);
      l[i] = l[i] * alpha + ps;
      m[i] = mnew;
#pragma unroll
      for (int j = 0; j < 4; j++) acc[i][j] *= alpha;
    }
    __syncthreads();   // all QK reads of Kd done before overwriting with P
    // write P into Kd as Ps[key][query]
#pragma unroll
    for (int i = 0; i < 4; i++)
#pragma unroll
      for (int j = 0; j < 4; j++) Kd[(tx << 2) + j][(ty << 2) + i] = s[i][j];
    __syncthreads();
    // O += P V — register tile, k over keys
#pragma unroll 8
    for (int jj = 0; jj < 64; jj++) {
      const float4 a = *(const float4*)&Kd[jj][ty << 2];
      const float4 b = *(const float4*)&Vt[jj][tx << 2];
      const float ar[4] = {a.x, a.y, a.z, a.w};
      const float br[4] = {b.x, b.y, b.z, b.w};
#pragma unroll
      for (int i = 0; i < 4; i++)
#pragma unroll
        for (int j = 0; j < 4; j++) acc[i][j] += ar[i] * br[j];
    }
  }
  // epilogue: O / l
#pragma unroll
  for (int i = 0; i < 4; i++) {
    const int t = qt * 64 + (ty << 2) + i;
    const float invl = 1.f / l[i];
    float4 o;
    o.x = acc[i][0] * invl; o.y = acc[i][1] * invl;
    o.z = acc[i][2] * invl; o.w = acc[i][3] * invl;
    *(float4*)(attn + (size_t)t * (NHH * HD) + h * HD + (tx << 2)) = o;
  }
}

// ---------------- router logits: lane e computes h2[t] . gate_w[e] ----------------
__global__ void gate_logits_k(const float* __restrict__ h2, const float* __restrict__ gw,
                              float* __restrict__ logits) {
  const int t = blockIdx.x;
  const int e = threadIdx.x;  // 64
  const float* hp = h2 + (size_t)t * H_DIM;
  const float* gp = gw + (size_t)e * H_DIM;
  float s = 0.f;
  for (int i = 0; i < H_DIM; i += 4) {
    const float4 h4 = *(const float4*)(hp + i);
    const float4 g4 = *(const float4*)(gp + i);
    s += h4.x * g4.x + h4.y * g4.y + h4.z * g4.z + h4.w * g4.w;
  }
  logits[t * NE + e] = s;
}

// ---------------- routing: one thread per token ----------------
__global__ void route_k(const float* __restrict__ logits, const float* __restrict__ ebias,
                        int* __restrict__ topk_ids, float* __restrict__ topk_w) {
  const int t = blockIdx.x * 64 + threadIdx.x;
  if (t >= T_TOK) return;
  float s[NE], sc[NE];
  const float* lp = logits + t * NE;
#pragma unroll
  for (int e = 0; e < NE; e++) {
    const float v = 1.f / (1.f + expf(-lp[e]));
    s[e] = v;
    sc[e] = v + ebias[e];
  }
  float gsc[NGRP];
#pragma unroll
  for (int gi = 0; gi < NGRP; gi++) {
    float m1 = -1e30f, m2 = -1e30f;
#pragma unroll
    for (int j = 0; j < 8; j++) {
      const float v = sc[gi * 8 + j];
      if (v > m1) { m2 = m1; m1 = v; } else if (v > m2) m2 = v;
    }
    gsc[gi] = m1 + m2;
  }
  unsigned gmask = 0;
  for (int k2 = 0; k2 < TKG; k2++) {
    int bi = 0; float b = -3.4e38f;
#pragma unroll
    for (int gi = 0; gi < NGRP; gi++)
      if (!((gmask >> gi) & 1u) && gsc[gi] > b) { b = gsc[gi]; bi = gi; }
    gmask |= 1u << bi;
  }
  unsigned long long esel = 0ull;
  float wsum = 0.f;
  int ids[TOPKK]; float wv[TOPKK];
  for (int k2 = 0; k2 < TOPKK; k2++) {
    int bi = 0; float b = -3.4e38f;
    for (int e = 0; e < NE; e++) {
      if (((gmask >> (e >> 3)) & 1u) && !((esel >> e) & 1ull) && sc[e] > b) { b = sc[e]; bi = e; }
    }
    esel |= 1ull << bi;
    ids[k2] = bi;
    wv[k2] = s[bi];
    wsum += wv[k2];
  }
  const float norm = 2.5f / (wsum + 1e-20f);
#pragma unroll
  for (int k2 = 0; k2 < TOPKK; k2++) {
    topk_ids[t * TOPKK + k2] = ids[k2];
    topk_w[t * TOPKK + k2] = wv[k2] * norm;
  }
}

// ---------------- expert-token list construction ----------------
__global__ void count_k(const int* __restrict__ ids, int* __restrict__ counts) {
  const int idx = blockIdx.x * 256 + threadIdx.x;
  if (idx < NPOS) atomicAdd(&counts[ids[idx]], 1);
}

__global__ void offsets_k(const int* __restrict__ counts, int* __restrict__ offsets,
                          int* __restrict__ cursor) {
  if (threadIdx.x == 0 && blockIdx.x == 0) {
    int acc = 0;
    for (int e = 0; e < NE; e++) { offsets[e] = acc; cursor[e] = acc; acc += counts[e]; }
    offsets[NE] = acc;
  }
}

__global__ void scatter_k(const int* __restrict__ ids, const float* __restrict__ wts,
                          int* __restrict__ cursor, int* __restrict__ perm_tok,
                          float* __restrict__ perm_w) {
  const int idx = blockIdx.x * 256 + threadIdx.x;
  if (idx >= NPOS) return;
  const int e = ids[idx];
  const int pos = atomicAdd(&cursor[e], 1);
  perm_tok[pos] = idx >> 3;   // token
  perm_w[pos] = wts[idx];
}

// ---------------- routed experts: gate+up+silu ----------------
__global__ void moe_gateup_k(const float* __restrict__ h2, const float* __restrict__ we_gate,
                             const float* __restrict__ we_up, const int* __restrict__ perm_tok,
                             const int* __restrict__ offsets, float* __restrict__ act) {
  const int e = blockIdx.z;
  const int base = offsets[e];
  const int cnt = offsets[e + 1] - base;
  const int n0 = blockIdx.y * 64;
  if (n0 >= cnt) return;
  const int i0 = blockIdx.x * 64;
  __shared__ float As[16][68];
  __shared__ float Bg[16][68];
  __shared__ float Bu[16][68];
  __shared__ int toks[64];
  const int tid = threadIdx.x;
  if (tid < 64) toks[tid] = perm_tok[base + min(n0 + tid, cnt - 1)];
  __syncthreads();
  const float* wg = we_gate + (size_t)e * H_DIM * EI;
  const float* wu = we_up + (size_t)e * H_DIM * EI;
  const int tx = tid & 15, ty = tid >> 4;
  const int am = tid >> 2, ak = (tid & 3) << 2;
  const int bk = tid >> 4, bn = (tid & 15) << 2;
  float accg[4][4] = {}, accu[4][4] = {};
  for (int kk = 0; kk < H_DIM; kk += 16) {
    const float4 av = *(const float4*)(h2 + (size_t)toks[am] * H_DIM + kk + ak);
    As[ak + 0][am] = av.x; As[ak + 1][am] = av.y;
    As[ak + 2][am] = av.z; As[ak + 3][am] = av.w;
    *(float4*)&Bg[bk][bn] = *(const float4*)(wg + (size_t)(kk + bk) * EI + i0 + bn);
    *(float4*)&Bu[bk][bn] = *(const float4*)(wu + (size_t)(kk + bk) * EI + i0 + bn);
    __syncthreads();
#pragma unroll
    for (int k = 0; k < 16; k++) {
      const float4 a = *(const float4*)&As[k][ty << 2];
      const float4 bg = *(const float4*)&Bg[k][tx << 2];
      const float4 bu = *(const float4*)&Bu[k][tx << 2];
      const float ar[4] = {a.x, a.y, a.z, a.w};
      const float bgr[4] = {bg.x, bg.y, bg.z, bg.w};
      const float bur[4] = {bu.x, bu.y, bu.z, bu.w};
#pragma unroll
      for (int i = 0; i < 4; i++)
#pragma unroll
        for (int j = 0; j < 4; j++) {
          accg[i][j] += ar[i] * bgr[j];
          accu[i][j] += ar[i] * bur[j];
        }
    }
    __syncthreads();
  }
#pragma unroll
  for (int i = 0; i < 4; i++) {
    const int n = n0 + (ty << 2) + i;
    if (n < cnt) {
#pragma unroll
      for (int j = 0; j < 4; j++) {
        const float gv = accg[i][j], uv = accu[i][j];
        act[(size_t)(base + n) * EI + i0 + (tx << 2) + j] = gv / (1.f + expf(-gv)) * uv;
      }
    }
  }
}

// ---------------- routed experts: down proj, weighted atomic accumulate into y -------
__global__ void moe_down_k(const float* __restrict__ act, const float* __restrict__ we_down,
                           const int* __restrict__ perm_tok, const float* __restrict__ perm_w,
                           const int* __restrict__ offsets, float* __restrict__ y) {
  const int e = blockIdx.z;
  const int base = offsets[e];
  const int cnt = offsets[e + 1] - base;
  const int n0 = blockIdx.y * 64;
  if (n0 >= cnt) return;
  const int h0 = blockIdx.x * 64;
  __shared__ float As[16][68];
  __shared__ float Bs[16][68];
  __shared__ int toks[64];
  __shared__ float wts[64];
  const int tid = threadIdx.x;
  if (tid < 64) {
    const int r = min(n0 + tid, cnt - 1);
    toks[tid] = perm_tok[base + r];
    wts[tid] = perm_w[base + r];
  }
  __syncthreads();
  const float* wd = we_down + (size_t)e * EI * H_DIM;
  const int tx = tid & 15, ty = tid >> 4;
  const int am = tid >> 2, ak = (tid & 3) << 2;
  const int bk = tid >> 4, bn = (tid & 15) << 2;
  const int ar_row = base + min(n0 + am, cnt - 1);
  float acc[4][4] = {};
  for (int kk = 0; kk < EI; kk += 16) {
    const float4 av = *(const float4*)(act + (size_t)ar_row * EI + kk + ak);
    As[ak + 0][am] = av.x; As[ak + 1][am] = av.y;
    As[ak + 2][am] = av.z; As[ak + 3][am] = av.w;
    *(float4*)&Bs[bk][bn] = *(const float4*)(wd + (size_t)(kk + bk) * H_DIM + h0 + bn);
    __syncthreads();
#pragma unroll
    for (int k = 0; k < 16; k++) {
      const float4 a = *(const float4*)&As[k][ty << 2];
      const float4 b = *(const float4*)&Bs[k][tx << 2];
      const float ar[4] = {a.x, a.y, a.z, a.w};
      const float br[4] = {b.x, b.y, b.z, b.w};
#pragma unroll
      for (int i = 0; i < 4; i++)
#pragma unroll
        for (int j = 0; j < 4; j++) acc[i][j] += ar[i] * br[j];
    }
    __syncthreads();
  }
#pragma unroll
  for (int i = 0; i < 4; i++) {
    const int n = n0 + (ty << 2) + i;
    if (n < cnt) {
      const float wv = wts[(ty << 2) + i];
      const int t = toks[(ty << 2) + i];
#pragma unroll
      for (int j = 0; j < 4; j++)
        atomicAdd(&y[(size_t)t * H_DIM + h0 + (tx << 2) + j], wv * acc[i][j]);
    }
  }
}

// ---------------- shared expert activation ----------------
__global__ void sact_k(const float* __restrict__ gu, float* __restrict__ sa) {
  const int idx = blockIdx.x * 256 + threadIdx.x;   // < T*512
  const int t = idx >> 9, i = idx & 511;
  const float g = gu[(size_t)t * 1024 + i];
  const float u = gu[(size_t)t * 1024 + 512 + i];
  sa[idx] = g / (1.f + expf(-g)) * u;
}

// ---------------- launch ----------------
extern "C" void kernel_launch(void* const* d_in, const int* in_sizes, int n_in,
                              void* d_out, int out_size, void* d_ws, size_t ws_size,
                              hipStream_t stream) {
  const float* x         = (const float*)d_in[0];
  const int*   positions = (const int*)d_in[1];
  const float* ln1_w     = (const float*)d_in[2];
  const float* w_qkv     = (const float*)d_in[3];
  const float* w_o       = (const float*)d_in[4];
  const float* ln2_w     = (const float*)d_in[5];
  const float* gate_w    = (const float*)d_in[6];
  const float* ebias     = (const float*)d_in[7];
  const float* we_gate   = (const float*)d_in[8];
  const float* we_up     = (const float*)d_in[9];
  const float* we_down   = (const float*)d_in[10];
  const float* ws_gateup = (const float*)d_in[11];
  const float* ws_down   = (const float*)d_in[12];
  float* out = (float*)d_out;

  char* wsp = (char*)d_ws;
  size_t off = 0;
  auto alloc = [&](size_t bytes) {
    void* p = wsp + off;
    off += (bytes + 255) & ~(size_t)255;
    return p;
  };
  float* h1      = (float*)alloc((size_t)T_TOK * H_DIM * 4);
  float* qkv     = (float*)alloc((size_t)T_TOK * QKV_N * 4);
  float* attn    = (float*)alloc((size_t)T_TOK * H_DIM * 4);
  float* resid1  = (float*)alloc((size_t)T_TOK * H_DIM * 4);
  float* h2      = (float*)alloc((size_t)T_TOK * H_DIM * 4);
  float* logits  = (float*)alloc((size_t)T_TOK * NE * 4);
  int*   tids    = (int*)alloc((size_t)NPOS * 4);
  float* tw      = (float*)alloc((size_t)NPOS * 4);
  int*   counts  = (int*)alloc(NE * 4);
  int*   offs    = (int*)alloc((NE + 1) * 4);
  int*   cursor  = (int*)alloc(NE * 4);
  int*   ptok    = (int*)alloc((size_t)NPOS * 4);
  float* pw      = (float*)alloc((size_t)NPOS * 4);
  float* act     = (float*)alloc((size_t)NPOS * EI * 4);
  float* y       = (float*)alloc((size_t)T_TOK * H_DIM * 4);
  float* gu      = (float*)alloc((size_t)T_TOK * 1024 * 4);
  float* sa      = (float*)alloc((size_t)T_TOK * ISH * 4);
  (void)ws_size; (void)in_sizes; (void)n_in; (void)out_size;

  hipMemsetAsync(counts, 0, NE * 4, stream);
  hipMemsetAsync(y, 0, (size_t)T_TOK * H_DIM * 4, stream);

  // attention block
  rmsnorm_k<<<T_TOK, 256, 0, stream>>>(x, ln1_w, h1);
  gemm64_k<<<dim3(QKV_N / 64, T_TOK / 64), 256, 0, stream>>>(
      h1, w_qkv, nullptr, nullptr, qkv, T_TOK, QKV_N, H_DIM);
  rope_k<<<dim3(T_TOK, NHH + NKVH), 32, 0, stream>>>(qkv, positions);
  attn_k<<<dim3(T_TOK / 64, NHH), 256, 0, stream>>>(qkv, attn);
  gemm64_k<<<dim3(H_DIM / 64, T_TOK / 64), 256, 0, stream>>>(
      attn, w_o, x, nullptr, resid1, T_TOK, H_DIM, H_DIM);

  // MoE block
  rmsnorm_k<<<T_TOK, 256, 0, stream>>>(resid1, ln2_w, h2);
  gate_logits_k<<<T_TOK, 64, 0, stream>>>(h2, gate_w, logits);
  route_k<<<T_TOK / 64, 64, 0, stream>>>(logits, ebias, tids, tw);
  count_k<<<NPOS / 256, 256, 0, stream>>>(tids, counts);
  offsets_k<<<1, 1, 0, stream>>>(counts, offs, cursor);
  scatter_k<<<NPOS / 256, 256, 0, stream>>>(tids, tw, cursor, ptok, pw);
  moe_gateup_k<<<dim3(EI / 64, T_TOK / 64, NE), 256, 0, stream>>>(
      h2, we_gate, we_up, ptok, offs, act);
  moe_down_k<<<dim3(H_DIM / 64, T_TOK / 64, NE), 256, 0, stream>>>(
      act, we_down, ptok, pw, offs, y);

  // shared expert + final combine
  gemm64_k<<<dim3(1024 / 64, T_TOK / 64), 256, 0, stream>>>(
      h2, ws_gateup, nullptr, nullptr, gu, T_TOK, 1024, H_DIM);
  sact_k<<<(T_TOK * ISH) / 256, 256, 0, stream>>>(gu, sa);
  gemm64_k<<<dim3(H_DIM / 64, T_TOK / 64), 256, 0, stream>>>(
      sa, ws_down, resid1, y, out, T_TOK, H_DIM, ISH);
}

// Round 3
// 1002.929 us; speedup vs baseline: 2.1049x; 1.4902x over previous
//
#include <hip/hip_runtime.h>
#include <hip/hip_bf16.h>
#include <math.h>

#define T_TOK 2048
#define H_DIM 1024
#define NHH 16
#define NKVH 4
#define HD 64
#define QKV_N 1536   // (16 + 2*4) * 64
#define NE 64
#define NGRP 8
#define TKG 4
#define TOPKK 8
#define EI 256
#define ISH 512
#define NPOS (T_TOK * TOPKK)   // 16384 expert-token slots

typedef __bf16 bf16_t;
typedef bf16_t bf16x8 __attribute__((ext_vector_type(8)));
typedef bf16_t bf16x4v __attribute__((ext_vector_type(4)));
typedef float f32x4 __attribute__((ext_vector_type(4)));

#define MFMA_BF16 __builtin_amdgcn_mfma_f32_16x16x32_bf16

// ---------------- RMSNorm -> optional f32 out + bf16 out ----------------
__global__ void rmsnorm_k(const float* __restrict__ x, const float* __restrict__ w,
                          float* __restrict__ outf, bf16_t* __restrict__ outb) {
  const int t = blockIdx.x;
  const int tid = threadIdx.x;
  const float* xp = x + (size_t)t * H_DIM;
  const float4 x4 = *(const float4*)(xp + tid * 4);
  float s = x4.x * x4.x + x4.y * x4.y + x4.z * x4.z + x4.w * x4.w;
#pragma unroll
  for (int off = 32; off >= 1; off >>= 1) s += __shfl_xor(s, off);
  __shared__ float red[4];
  if ((tid & 63) == 0) red[tid >> 6] = s;
  __syncthreads();
  const float tot = red[0] + red[1] + red[2] + red[3];
  const float r = rsqrtf(tot / (float)H_DIM + 1e-6f);
  const float4 w4 = *(const float4*)(w + tid * 4);
  float4 o;
  o.x = x4.x * r * w4.x; o.y = x4.y * r * w4.y;
  o.z = x4.z * r * w4.z; o.w = x4.w * r * w4.w;
  if (outf) *(float4*)(outf + (size_t)t * H_DIM + tid * 4) = o;
  bf16x4v ob;
  ob[0] = (bf16_t)o.x; ob[1] = (bf16_t)o.y; ob[2] = (bf16_t)o.z; ob[3] = (bf16_t)o.w;
  *(bf16x4v*)(outb + (size_t)t * H_DIM + tid * 4) = ob;
}

// ---------------- transpose-cast f32 [R][C] -> bf16 [C][R] (per-expert strides) ----
__global__ void castT_k(const float* __restrict__ src, bf16_t* __restrict__ dst,
                        int R, int C, size_t srcStride, size_t dstStride,
                        int dstLD, int rowOff) {
  const int e = blockIdx.z;
  const float* sp = src + (size_t)e * srcStride;
  bf16_t* dp = dst + (size_t)e * dstStride;
  const int r0 = blockIdx.y * 32, c0 = blockIdx.x * 32;
  const int tid = threadIdx.x;
  __shared__ float tl[32][33];
  {
    const int rr = tid >> 3, cc4 = (tid & 7) * 4;
    const float4 v = *(const float4*)(sp + (size_t)(r0 + rr) * C + c0 + cc4);
    tl[rr][cc4 + 0] = v.x; tl[rr][cc4 + 1] = v.y;
    tl[rr][cc4 + 2] = v.z; tl[rr][cc4 + 3] = v.w;
  }
  __syncthreads();
  {
    const int cc = tid >> 3, rr4 = (tid & 7) * 4;
    bf16x4v o;
#pragma unroll
    for (int i = 0; i < 4; i++) o[i] = (bf16_t)tl[rr4 + i][cc];
    *(bf16x4v*)(dp + (size_t)(rowOff + c0 + cc) * dstLD + r0 + rr4) = o;
  }
}

// ---------------- MFMA GEMM: C[M,N] f32 = A[M,K]bf16 @ Bt[N,K]bf16 (+add0)(+add1) ----
// 256 thr = 4 waves (2x2), tile 128x128, BK=64, fragment-major LDS.
__global__ __launch_bounds__(256) void mfma_gemm_k(
    const bf16_t* __restrict__ A, const bf16_t* __restrict__ Bt,
    const float* __restrict__ add0, const float* __restrict__ add1,
    float* __restrict__ C, int M, int N, int K) {
  __shared__ bf16_t Al[128 * 64];
  __shared__ bf16_t Bl[128 * 64];
  const int tid = threadIdx.x;
  const int lane = tid & 63, wave = tid >> 6;
  const int wm = wave >> 1, wn = wave & 1;
  const int lrow = lane & 15, lq = lane >> 4;
  const int m0 = blockIdx.y * 128, n0 = blockIdx.x * 128;
  const int arow = tid >> 1, qb = (tid & 1) * 4;
  const bf16_t* Arow = A + (size_t)(m0 + arow) * K + qb * 8;
  const bf16_t* Brow = Bt + (size_t)(n0 + arow) * K + qb * 8;
  f32x4 acc[4][4];
#pragma unroll
  for (int i = 0; i < 4; i++)
#pragma unroll
    for (int j = 0; j < 4; j++) acc[i][j] = (f32x4){0.f, 0.f, 0.f, 0.f};
  for (int k0 = 0; k0 < K; k0 += 64) {
    __syncthreads();
#pragma unroll
    for (int i = 0; i < 4; i++) {
      const int q = qb + i;
      *(bf16x8*)&Al[(q * 128 + arow) * 8] = *(const bf16x8*)(Arow + k0 + i * 8);
      *(bf16x8*)&Bl[(q * 128 + arow) * 8] = *(const bf16x8*)(Brow + k0 + i * 8);
    }
    __syncthreads();
#pragma unroll
    for (int kb = 0; kb < 2; kb++) {
      bf16x8 af[4], bfr[4];
#pragma unroll
      for (int i = 0; i < 4; i++) {
        af[i]  = *(const bf16x8*)&Al[((kb * 4 + lq) * 128 + wm * 64 + i * 16 + lrow) * 8];
        bfr[i] = *(const bf16x8*)&Bl[((kb * 4 + lq) * 128 + wn * 64 + i * 16 + lrow) * 8];
      }
#pragma unroll
      for (int i = 0; i < 4; i++)
#pragma unroll
        for (int j = 0; j < 4; j++)
          acc[i][j] = MFMA_BF16(af[i], bfr[j], acc[i][j], 0, 0, 0);
    }
  }
#pragma unroll
  for (int i = 0; i < 4; i++)
#pragma unroll
    for (int r = 0; r < 4; r++) {
      const int m = m0 + wm * 64 + i * 16 + lq * 4 + r;
#pragma unroll
      for (int j = 0; j < 4; j++) {
        const int n = n0 + wn * 64 + j * 16 + lrow;
        float v = acc[i][j][r];
        if (add0) v += add0[(size_t)m * N + n];
        if (add1) v += add1[(size_t)m * N + n];
        C[(size_t)m * N + n] = v;
      }
    }
}

// ---------------- MoE gate+up grouped MFMA GEMM: rows gathered via ptok ----------
// N=512 (gate cols 0..255, up cols 256..511 in weT), K=1024; out bf16 gu_e.
__global__ __launch_bounds__(256) void mfma_gateup_k(
    const bf16_t* __restrict__ h2b, const bf16_t* __restrict__ weT,
    const int* __restrict__ ptok, const int* __restrict__ offs,
    bf16_t* __restrict__ gu_e) {
  const int e = blockIdx.z;
  const int base = offs[e];
  const int cnt = offs[e + 1] - base;
  const int m0 = blockIdx.y * 128;
  if (m0 >= cnt) return;
  const int n0 = blockIdx.x * 128;
  __shared__ bf16_t Al[128 * 64];
  __shared__ bf16_t Bl[128 * 64];
  __shared__ int toks[128];
  const int tid = threadIdx.x;
  if (tid < 128) toks[tid] = ptok[base + min(m0 + tid, cnt - 1)];
  const int lane = tid & 63, wave = tid >> 6;
  const int wm = wave >> 1, wn = wave & 1;
  const int lrow = lane & 15, lq = lane >> 4;
  const int arow = tid >> 1, qb = (tid & 1) * 4;
  const bf16_t* Bt = weT + (size_t)e * 512 * 1024;
  const bf16_t* Brow = Bt + (size_t)(n0 + arow) * 1024 + qb * 8;
  f32x4 acc[4][4];
#pragma unroll
  for (int i = 0; i < 4; i++)
#pragma unroll
    for (int j = 0; j < 4; j++) acc[i][j] = (f32x4){0.f, 0.f, 0.f, 0.f};
  for (int k0 = 0; k0 < 1024; k0 += 64) {
    __syncthreads();
    const bf16_t* Arow = h2b + (size_t)toks[arow] * 1024 + qb * 8;
#pragma unroll
    for (int i = 0; i < 4; i++) {
      const int q = qb + i;
      *(bf16x8*)&Al[(q * 128 + arow) * 8] = *(const bf16x8*)(Arow + k0 + i * 8);
      *(bf16x8*)&Bl[(q * 128 + arow) * 8] = *(const bf16x8*)(Brow + k0 + i * 8);
    }
    __syncthreads();
#pragma unroll
    for (int kb = 0; kb < 2; kb++) {
      bf16x8 af[4], bfr[4];
#pragma unroll
      for (int i = 0; i < 4; i++) {
        af[i]  = *(const bf16x8*)&Al[((kb * 4 + lq) * 128 + wm * 64 + i * 16 + lrow) * 8];
        bfr[i] = *(const bf16x8*)&Bl[((kb * 4 + lq) * 128 + wn * 64 + i * 16 + lrow) * 8];
      }
#pragma unroll
      for (int i = 0; i < 4; i++)
#pragma unroll
        for (int j = 0; j < 4; j++)
          acc[i][j] = MFMA_BF16(af[i], bfr[j], acc[i][j], 0, 0, 0);
    }
  }
#pragma unroll
  for (int i = 0; i < 4; i++)
#pragma unroll
    for (int r = 0; r < 4; r++) {
      const int mloc = m0 + wm * 64 + i * 16 + lq * 4 + r;
      if (mloc < cnt) {
#pragma unroll
        for (int j = 0; j < 4; j++) {
          const int n = n0 + wn * 64 + j * 16 + lrow;
          gu_e[(size_t)(base + mloc) * 512 + n] = (bf16_t)acc[i][j][r];
        }
      }
    }
}

// ---------------- MoE down grouped MFMA GEMM: weighted atomicAdd into y ----------
// A = actb rows (already permuted), N=1024, K=256.
__global__ __launch_bounds__(256) void mfma_down_k(
    const bf16_t* __restrict__ actb, const bf16_t* __restrict__ wdT,
    const int* __restrict__ ptok, const float* __restrict__ pw,
    const int* __restrict__ offs, float* __restrict__ y) {
  const int e = blockIdx.z;
  const int base = offs[e];
  const int cnt = offs[e + 1] - base;
  const int m0 = blockIdx.y * 128;
  if (m0 >= cnt) return;
  const int n0 = blockIdx.x * 128;
  __shared__ bf16_t Al[128 * 64];
  __shared__ bf16_t Bl[128 * 64];
  const int tid = threadIdx.x;
  const int lane = tid & 63, wave = tid >> 6;
  const int wm = wave >> 1, wn = wave & 1;
  const int lrow = lane & 15, lq = lane >> 4;
  const int arow = tid >> 1, qb = (tid & 1) * 4;
  const int agrow = base + min(m0 + arow, cnt - 1);
  const bf16_t* Arow = actb + (size_t)agrow * 256 + qb * 8;
  const bf16_t* Brow = wdT + (size_t)e * 1024 * 256 + (size_t)(n0 + arow) * 256 + qb * 8;
  f32x4 acc[4][4];
#pragma unroll
  for (int i = 0; i < 4; i++)
#pragma unroll
    for (int j = 0; j < 4; j++) acc[i][j] = (f32x4){0.f, 0.f, 0.f, 0.f};
  for (int k0 = 0; k0 < 256; k0 += 64) {
    __syncthreads();
#pragma unroll
    for (int i = 0; i < 4; i++) {
      const int q = qb + i;
      *(bf16x8*)&Al[(q * 128 + arow) * 8] = *(const bf16x8*)(Arow + k0 + i * 8);
      *(bf16x8*)&Bl[(q * 128 + arow) * 8] = *(const bf16x8*)(Brow + k0 + i * 8);
    }
    __syncthreads();
#pragma unroll
    for (int kb = 0; kb < 2; kb++) {
      bf16x8 af[4], bfr[4];
#pragma unroll
      for (int i = 0; i < 4; i++) {
        af[i]  = *(const bf16x8*)&Al[((kb * 4 + lq) * 128 + wm * 64 + i * 16 + lrow) * 8];
        bfr[i] = *(const bf16x8*)&Bl[((kb * 4 + lq) * 128 + wn * 64 + i * 16 + lrow) * 8];
      }
#pragma unroll
      for (int i = 0; i < 4; i++)
#pragma unroll
        for (int j = 0; j < 4; j++)
          acc[i][j] = MFMA_BF16(af[i], bfr[j], acc[i][j], 0, 0, 0);
    }
  }
#pragma unroll
  for (int i = 0; i < 4; i++)
#pragma unroll
    for (int r = 0; r < 4; r++) {
      const int mloc = m0 + wm * 64 + i * 16 + lq * 4 + r;
      if (mloc < cnt) {
        const float wv = pw[base + mloc];
        const int tok = ptok[base + mloc];
#pragma unroll
        for (int j = 0; j < 4; j++) {
          const int n = n0 + wn * 64 + j * 16 + lrow;
          atomicAdd(&y[(size_t)tok * H_DIM + n], wv * acc[i][j][r]);
        }
      }
    }
}

// ---------------- RoPE (neox, in-place on q and k regions of qkv), f32 ----------------
__global__ void rope_k(float* __restrict__ qkv, const int* __restrict__ positions) {
  const int t = blockIdx.x, h = blockIdx.y;
  const int i = threadIdx.x;                  // 0..31
  const float inv = exp2f((float)i * (-13.287712379549449f / 32.0f));
  const float f = (float)positions[t] * inv;
  float sn, c;
  sincosf(f, &sn, &c);
  float* p = qkv + (size_t)t * QKV_N + h * HD;
  const float x1 = p[i], x2 = p[i + 32];
  p[i] = x1 * c - x2 * sn;
  p[i + 32] = x2 * c + x1 * sn;
}

// ---------------- flash attention (f32), bf16 output ----------------
__global__ __launch_bounds__(256) void attn_k(const float* __restrict__ qkv,
                                              bf16_t* __restrict__ attnb) {
  const int qt = (T_TOK / 64 - 1) - blockIdx.x;   // heavy tiles first
  const int h = blockIdx.y;
  const int g = h >> 2;
  const int tid = threadIdx.x;
  const int tx = tid & 15, ty = tid >> 4;
  __shared__ float Qt[64][68];
  __shared__ float Kd[64][68];
  __shared__ float Vt[64][68];
  {
    const int i = tid & 63, dg = tid >> 6;
    const float* qp = qkv + (size_t)(qt * 64 + i) * QKV_N + h * HD;
#pragma unroll
    for (int r = 0; r < 4; r++) {
      const int d = dg * 16 + r * 4;
      const float4 v = *(const float4*)(qp + d);
      Qt[d + 0][i] = v.x * 0.125f;
      Qt[d + 1][i] = v.y * 0.125f;
      Qt[d + 2][i] = v.z * 0.125f;
      Qt[d + 3][i] = v.w * 0.125f;
    }
  }
  float m[4], l[4], acc[4][4];
#pragma unroll
  for (int i = 0; i < 4; i++) {
    m[i] = -1e30f; l[i] = 0.f;
#pragma unroll
    for (int j = 0; j < 4; j++) acc[i][j] = 0.f;
  }
  const float* kbase = qkv + NHH * HD + g * HD;
  const float* vbase = qkv + (NHH + NKVH) * HD + g * HD;
  const int jj_stage = tid & 63, dg_stage = tid >> 6;
  for (int s0 = 0; s0 <= qt * 64; s0 += 64) {
    __syncthreads();
    {
      const float* kp = kbase + (size_t)(s0 + jj_stage) * QKV_N;
      const float* vp = vbase + (size_t)(s0 + jj_stage) * QKV_N;
#pragma unroll
      for (int r = 0; r < 4; r++) {
        const int d = dg_stage * 16 + r * 4;
        const float4 k4 = *(const float4*)(kp + d);
        Kd[d + 0][jj_stage] = k4.x; Kd[d + 1][jj_stage] = k4.y;
        Kd[d + 2][jj_stage] = k4.z; Kd[d + 3][jj_stage] = k4.w;
        *(float4*)&Vt[jj_stage][d] = *(const float4*)(vp + d);
      }
    }
    __syncthreads();
    float s[4][4] = {};
#pragma unroll 8
    for (int d = 0; d < 64; d++) {
      const float4 a = *(const float4*)&Qt[d][ty << 2];
      const float4 b = *(const float4*)&Kd[d][tx << 2];
      const float ar[4] = {a.x, a.y, a.z, a.w};
      const float br[4] = {b.x, b.y, b.z, b.w};
#pragma unroll
      for (int i = 0; i < 4; i++)
#pragma unroll
        for (int j = 0; j < 4; j++) s[i][j] += ar[i] * br[j];
    }
    if (s0 == qt * 64) {
#pragma unroll
      for (int i = 0; i < 4; i++)
#pragma unroll
        for (int j = 0; j < 4; j++)
          if ((tx << 2) + j > (ty << 2) + i) s[i][j] = -1e30f;
    }
#pragma unroll
    for (int i = 0; i < 4; i++) {
      float mx = fmaxf(fmaxf(s[i][0], s[i][1]), fmaxf(s[i][2], s[i][3]));
#pragma unroll
      for (int off = 1; off <= 8; off <<= 1) mx = fmaxf(mx, __shfl_xor(mx, off));
      const float mnew = fmaxf(m[i], mx);
      const float alpha = expf(m[i] - mnew);
      float ps = 0.f;
#pragma unroll
      for (int j = 0; j < 4; j++) { const float p = expf(s[i][j] - mnew); s[i][j] = p; ps += p; }
#pragma unroll
      for (int off = 1; off <= 8; off <<= 1) ps += __shfl_xor(ps, off);
      l[i] = l[i] * alpha + ps;
      m[i] = mnew;
#pragma unroll
      for (int j = 0; j < 4; j++) acc[i][j] *= alpha;
    }
    __syncthreads();
#pragma unroll
    for (int i = 0; i < 4; i++)
#pragma unroll
      for (int j = 0; j < 4; j++) Kd[(tx << 2) + j][(ty << 2) + i] = s[i][j];
    __syncthreads();
#pragma unroll 8
    for (int jj = 0; jj < 64; jj++) {
      const float4 a = *(const float4*)&Kd[jj][ty << 2];
      const float4 b = *(const float4*)&Vt[jj][tx << 2];
      const float ar[4] = {a.x, a.y, a.z, a.w};
      const float br[4] = {b.x, b.y, b.z, b.w};
#pragma unroll
      for (int i = 0; i < 4; i++)
#pragma unroll
        for (int j = 0; j < 4; j++) acc[i][j] += ar[i] * br[j];
    }
  }
#pragma unroll
  for (int i = 0; i < 4; i++) {
    const int t = qt * 64 + (ty << 2) + i;
    const float invl = 1.f / l[i];
    bf16x4v o;
    o[0] = (bf16_t)(acc[i][0] * invl); o[1] = (bf16_t)(acc[i][1] * invl);
    o[2] = (bf16_t)(acc[i][2] * invl); o[3] = (bf16_t)(acc[i][3] * invl);
    *(bf16x4v*)(attnb + (size_t)t * (NHH * HD) + h * HD + (tx << 2)) = o;
  }
}

// ---------------- router logits (f32 h2) ----------------
__global__ void gate_logits_k(const float* __restrict__ h2, const float* __restrict__ gw,
                              float* __restrict__ logits) {
  const int t = blockIdx.x;
  const int e = threadIdx.x;  // 64
  const float* hp = h2 + (size_t)t * H_DIM;
  const float* gp = gw + (size_t)e * H_DIM;
  float s = 0.f;
  for (int i = 0; i < H_DIM; i += 4) {
    const float4 h4 = *(const float4*)(hp + i);
    const float4 g4 = *(const float4*)(gp + i);
    s += h4.x * g4.x + h4.y * g4.y + h4.z * g4.z + h4.w * g4.w;
  }
  logits[t * NE + e] = s;
}

// ---------------- routing: one thread per token ----------------
__global__ void route_k(const float* __restrict__ logits, const float* __restrict__ ebias,
                        int* __restrict__ topk_ids, float* __restrict__ topk_w) {
  const int t = blockIdx.x * 64 + threadIdx.x;
  if (t >= T_TOK) return;
  float s[NE], sc[NE];
  const float* lp = logits + t * NE;
#pragma unroll
  for (int e = 0; e < NE; e++) {
    const float v = 1.f / (1.f + expf(-lp[e]));
    s[e] = v;
    sc[e] = v + ebias[e];
  }
  float gsc[NGRP];
#pragma unroll
  for (int gi = 0; gi < NGRP; gi++) {
    float m1 = -1e30f, m2 = -1e30f;
#pragma unroll
    for (int j = 0; j < 8; j++) {
      const float v = sc[gi * 8 + j];
      if (v > m1) { m2 = m1; m1 = v; } else if (v > m2) m2 = v;
    }
    gsc[gi] = m1 + m2;
  }
  unsigned gmask = 0;
  for (int k2 = 0; k2 < TKG; k2++) {
    int bi = 0; float b = -3.4e38f;
#pragma unroll
    for (int gi = 0; gi < NGRP; gi++)
      if (!((gmask >> gi) & 1u) && gsc[gi] > b) { b = gsc[gi]; bi = gi; }
    gmask |= 1u << bi;
  }
  unsigned long long esel = 0ull;
  float wsum = 0.f;
  int ids[TOPKK]; float wv[TOPKK];
  for (int k2 = 0; k2 < TOPKK; k2++) {
    int bi = 0; float b = -3.4e38f;
    for (int e = 0; e < NE; e++) {
      if (((gmask >> (e >> 3)) & 1u) && !((esel >> e) & 1ull) && sc[e] > b) { b = sc[e]; bi = e; }
    }
    esel |= 1ull << bi;
    ids[k2] = bi;
    wv[k2] = s[bi];
    wsum += wv[k2];
  }
  const float norm = 2.5f / (wsum + 1e-20f);
#pragma unroll
  for (int k2 = 0; k2 < TOPKK; k2++) {
    topk_ids[t * TOPKK + k2] = ids[k2];
    topk_w[t * TOPKK + k2] = wv[k2] * norm;
  }
}

// ---------------- expert-token list construction ----------------
__global__ void count_k(const int* __restrict__ ids, int* __restrict__ counts) {
  const int idx = blockIdx.x * 256 + threadIdx.x;
  if (idx < NPOS) atomicAdd(&counts[ids[idx]], 1);
}

__global__ void offsets_k(const int* __restrict__ counts, int* __restrict__ offsets,
                          int* __restrict__ cursor) {
  if (threadIdx.x == 0 && blockIdx.x == 0) {
    int acc = 0;
    for (int e = 0; e < NE; e++) { offsets[e] = acc; cursor[e] = acc; acc += counts[e]; }
    offsets[NE] = acc;
  }
}

__global__ void scatter_k(const int* __restrict__ ids, const float* __restrict__ wts,
                          int* __restrict__ cursor, int* __restrict__ perm_tok,
                          float* __restrict__ perm_w) {
  const int idx = blockIdx.x * 256 + threadIdx.x;
  if (idx >= NPOS) return;
  const int e = ids[idx];
  const int pos = atomicAdd(&cursor[e], 1);
  perm_tok[pos] = idx >> 3;
  perm_w[pos] = wts[idx];
}

// ---------------- silu(g)*u from gu_e bf16 -> act bf16 ----------------
__global__ void act2_k(const bf16_t* __restrict__ gu_e, bf16_t* __restrict__ actb) {
  const int row = blockIdx.x;
  const int c = threadIdx.x;   // 0..255
  const float g = (float)gu_e[(size_t)row * 512 + c];
  const float u = (float)gu_e[(size_t)row * 512 + 256 + c];
  actb[(size_t)row * 256 + c] = (bf16_t)(g / (1.f + expf(-g)) * u);
}

// ---------------- shared expert activation: gu f32 -> sa bf16 ----------------
__global__ void sact_k(const float* __restrict__ gu, bf16_t* __restrict__ sa) {
  const int idx = blockIdx.x * 256 + threadIdx.x;   // < T*512
  const int t = idx >> 9, i = idx & 511;
  const float g = gu[(size_t)t * 1024 + i];
  const float u = gu[(size_t)t * 1024 + 512 + i];
  sa[idx] = (bf16_t)(g / (1.f + expf(-g)) * u);
}

// ---------------- launch ----------------
extern "C" void kernel_launch(void* const* d_in, const int* in_sizes, int n_in,
                              void* d_out, int out_size, void* d_ws, size_t ws_size,
                              hipStream_t stream) {
  const float* x         = (const float*)d_in[0];
  const int*   positions = (const int*)d_in[1];
  const float* ln1_w     = (const float*)d_in[2];
  const float* w_qkv     = (const float*)d_in[3];
  const float* w_o       = (const float*)d_in[4];
  const float* ln2_w     = (const float*)d_in[5];
  const float* gate_w    = (const float*)d_in[6];
  const float* ebias     = (const float*)d_in[7];
  const float* we_gate   = (const float*)d_in[8];
  const float* we_up     = (const float*)d_in[9];
  const float* we_down   = (const float*)d_in[10];
  const float* ws_gateup = (const float*)d_in[11];
  const float* ws_down   = (const float*)d_in[12];
  float* out = (float*)d_out;

  char* wsp = (char*)d_ws;
  size_t off = 0;
  auto alloc = [&](size_t bytes) {
    void* p = wsp + off;
    off += (bytes + 255) & ~(size_t)255;
    return p;
  };
  // qkv (12 MiB) + attnb (4 MiB) are contiguous; gu_e (16 MiB bf16) aliases both.
  float*  qkv    = (float*)alloc((size_t)T_TOK * QKV_N * 4);
  bf16_t* attnb  = (bf16_t*)alloc((size_t)T_TOK * H_DIM * 2);
  bf16_t* gu_e   = (bf16_t*)qkv;                       // [NPOS][512] bf16, used after attnb dead
  bf16_t* h1b    = (bf16_t*)alloc((size_t)T_TOK * H_DIM * 2);
  bf16_t* sa     = h1b;                                // [T][512] bf16, used after h1b dead
  float*  resid1 = (float*)alloc((size_t)T_TOK * H_DIM * 4);
  float*  h2f    = (float*)alloc((size_t)T_TOK * H_DIM * 4);
  bf16_t* h2b    = (bf16_t*)alloc((size_t)T_TOK * H_DIM * 2);
  float*  logits = (float*)alloc((size_t)T_TOK * NE * 4);
  int*    tids   = (int*)alloc((size_t)NPOS * 4);
  float*  tw     = (float*)alloc((size_t)NPOS * 4);
  int*    counts = (int*)alloc(NE * 4);
  int*    offs   = (int*)alloc((NE + 1) * 4);
  int*    cursor = (int*)alloc(NE * 4);
  int*    ptok   = (int*)alloc((size_t)NPOS * 4);
  float*  pw     = (float*)alloc((size_t)NPOS * 4);
  bf16_t* actb   = (bf16_t*)alloc((size_t)NPOS * EI * 2);
  float*  y      = (float*)alloc((size_t)T_TOK * H_DIM * 4);
  float*  gu     = (float*)alloc((size_t)T_TOK * 1024 * 4);
  // bf16 transposed weights
  bf16_t* wqkvT  = (bf16_t*)alloc((size_t)QKV_N * H_DIM * 2);
  bf16_t* woT    = (bf16_t*)alloc((size_t)H_DIM * H_DIM * 2);
  bf16_t* wsguT  = (bf16_t*)alloc((size_t)1024 * H_DIM * 2);
  bf16_t* wsdT   = (bf16_t*)alloc((size_t)H_DIM * ISH * 2);
  bf16_t* weT    = (bf16_t*)alloc((size_t)NE * 512 * H_DIM * 2);
  bf16_t* wdT    = (bf16_t*)alloc((size_t)NE * H_DIM * EI * 2);
  (void)ws_size; (void)in_sizes; (void)n_in; (void)out_size;

  // weight casts (transpose to [N][K] bf16)
  castT_k<<<dim3(QKV_N / 32, H_DIM / 32, 1), 256, 0, stream>>>(
      w_qkv, wqkvT, H_DIM, QKV_N, 0, 0, H_DIM, 0);
  castT_k<<<dim3(H_DIM / 32, H_DIM / 32, 1), 256, 0, stream>>>(
      w_o, woT, H_DIM, H_DIM, 0, 0, H_DIM, 0);
  castT_k<<<dim3(1024 / 32, H_DIM / 32, 1), 256, 0, stream>>>(
      ws_gateup, wsguT, H_DIM, 1024, 0, 0, H_DIM, 0);
  castT_k<<<dim3(H_DIM / 32, ISH / 32, 1), 256, 0, stream>>>(
      ws_down, wsdT, ISH, H_DIM, 0, 0, ISH, 0);
  castT_k<<<dim3(EI / 32, H_DIM / 32, NE), 256, 0, stream>>>(
      we_gate, weT, H_DIM, EI, (size_t)H_DIM * EI, (size_t)512 * H_DIM, H_DIM, 0);
  castT_k<<<dim3(EI / 32, H_DIM / 32, NE), 256, 0, stream>>>(
      we_up, weT, H_DIM, EI, (size_t)H_DIM * EI, (size_t)512 * H_DIM, H_DIM, 256);
  castT_k<<<dim3(H_DIM / 32, EI / 32, NE), 256, 0, stream>>>(
      we_down, wdT, EI, H_DIM, (size_t)EI * H_DIM, (size_t)H_DIM * EI, EI, 0);

  hipMemsetAsync(counts, 0, NE * 4, stream);
  hipMemsetAsync(y, 0, (size_t)T_TOK * H_DIM * 4, stream);

  // attention block
  rmsnorm_k<<<T_TOK, 256, 0, stream>>>(x, ln1_w, nullptr, h1b);
  mfma_gemm_k<<<dim3(QKV_N / 128, T_TOK / 128), 256, 0, stream>>>(
      h1b, wqkvT, nullptr, nullptr, qkv, T_TOK, QKV_N, H_DIM);
  rope_k<<<dim3(T_TOK, NHH + NKVH), 32, 0, stream>>>(qkv, positions);
  attn_k<<<dim3(T_TOK / 64, NHH), 256, 0, stream>>>(qkv, attnb);
  mfma_gemm_k<<<dim3(H_DIM / 128, T_TOK / 128), 256, 0, stream>>>(
      attnb, woT, x, nullptr, resid1, T_TOK, H_DIM, H_DIM);

  // MoE routing
  rmsnorm_k<<<T_TOK, 256, 0, stream>>>(resid1, ln2_w, h2f, h2b);
  gate_logits_k<<<T_TOK, 64, 0, stream>>>(h2f, gate_w, logits);
  route_k<<<T_TOK / 64, 64, 0, stream>>>(logits, ebias, tids, tw);
  count_k<<<NPOS / 256, 256, 0, stream>>>(tids, counts);
  offsets_k<<<1, 1, 0, stream>>>(counts, offs, cursor);
  scatter_k<<<NPOS / 256, 256, 0, stream>>>(tids, tw, cursor, ptok, pw);

  // routed experts (gu_e aliases qkv+attnb — both dead by now)
  mfma_gateup_k<<<dim3(512 / 128, T_TOK / 128, NE), 256, 0, stream>>>(
      h2b, weT, ptok, offs, gu_e);
  act2_k<<<NPOS, 256, 0, stream>>>(gu_e, actb);
  mfma_down_k<<<dim3(H_DIM / 128, T_TOK / 128, NE), 256, 0, stream>>>(
      actb, wdT, ptok, pw, offs, y);

  // shared expert + final combine
  mfma_gemm_k<<<dim3(1024 / 128, T_TOK / 128), 256, 0, stream>>>(
      h2b, wsguT, nullptr, nullptr, gu, T_TOK, 1024, H_DIM);
  sact_k<<<(T_TOK * ISH) / 256, 256, 0, stream>>>(gu, sa);
  mfma_gemm_k<<<dim3(H_DIM / 128, T_TOK / 128), 256, 0, stream>>>(
      sa, wsdT, resid1, y, out, T_TOK, H_DIM, ISH);
}